// Round 15
// baseline (629.288 us; speedup 1.0000x reference)
//
#include <hip/hip_runtime.h>
#include <hip/hip_fp16.h>

#define N_USERS 100000
#define N_ITEMS 100000
#define N_NODES 200000
#define NNZ     3200000
#define EMB     64
#define HOPS    3
#define SLOTS   (HOPS + 1)
#define ROWSTRIDE (SLOTS * EMB)   // 256 floats per node row in out

#define BROWS 1024                               // rows per bucket
#define NBUCK ((N_NODES + BROWS - 1) / BROWS)    // 196
#define CAPB  20                                 // reg entries per thread (csr_bucket)
#define EPB   2048                               // edges per round (bucketize)
#define TILE  64                                 // nodes per transform block
#define LPAD  33                                 // LDS row pitch

// CSR entry: cv = (col<<14) | val14 ; ego mirror: int8 + per-row scale esc
// per-hop edge weight: wn[e] = fp16(val * esc[col]) (streaming, rebuilt per hop)
// side staged in fp16 buffer sideH (aliases build-only rl region)

// ---------------------------------------------------------------------------
__global__ __launch_bounds__(256) void init_ego_q(
    const float* __restrict__ user_emb,
    const float* __restrict__ item_emb,
    float* __restrict__ out,
    signed char* __restrict__ ego8, float* __restrict__ esc)
{
    int gid = blockIdx.x * blockDim.x + threadIdx.x;
    int n = gid >> 6;
    int d = gid & 63;
    if (n >= N_NODES) return;
    float v = (n < N_USERS) ? user_emb[(size_t)n * EMB + d]
                            : item_emb[(size_t)(n - N_USERS) * EMB + d];
    out[(size_t)n * ROWSTRIDE + d] = v;

    float mx = fabsf(v);
    #pragma unroll
    for (int o = 32; o > 0; o >>= 1) mx = fmaxf(mx, __shfl_xor(mx, o));
    float inv = (mx > 0.f) ? 127.f / mx : 0.f;
    ego8[(size_t)n * EMB + d] = (signed char)__float2int_rn(v * inv);
    if (d == 0) esc[n] = mx * (1.f / 127.f);
}

// ---------------------------------------------------------------------------
__global__ __launch_bounds__(256) void hist_buckets(
    const int4* __restrict__ rows4, int* __restrict__ bcnt)
{
    __shared__ int h[NBUCK];
    int t = threadIdx.x;
    if (t < NBUCK) h[t] = 0;
    __syncthreads();
    for (int i = blockIdx.x * blockDim.x + t; i < NNZ / 4; i += gridDim.x * blockDim.x) {
        int4 r = rows4[i];
        atomicAdd(&h[r.x >> 10], 1);
        atomicAdd(&h[r.y >> 10], 1);
        atomicAdd(&h[r.z >> 10], 1);
        atomicAdd(&h[r.w >> 10], 1);
    }
    __syncthreads();
    if (t < NBUCK && h[t]) atomicAdd(&bcnt[t], h[t]);
}

// ---------------------------------------------------------------------------
__global__ __launch_bounds__(256) void scan196(
    const int* __restrict__ bcnt, int* __restrict__ boff,
    int* __restrict__ gcur, int* __restrict__ off)
{
    __shared__ int sdata[256];
    int t = threadIdx.x;
    int v = (t < NBUCK) ? bcnt[t] : 0;
    sdata[t] = v;
    __syncthreads();
    #pragma unroll
    for (int ofs = 1; ofs < 256; ofs <<= 1) {
        int add = (t >= ofs) ? sdata[t - ofs] : 0;
        __syncthreads();
        sdata[t] += add;
        __syncthreads();
    }
    if (t < NBUCK) {
        int excl = sdata[t] - v;
        boff[t] = excl;
        gcur[t] = excl;
    }
    if (t == NBUCK - 1) boff[NBUCK] = sdata[t];
    if (t == 0) off[N_NODES] = NNZ;
}

// ---------------------------------------------------------------------------
__global__ __launch_bounds__(256) void bucketize(
    const int* __restrict__ rows, const int* __restrict__ cols,
    const float* __restrict__ vals,
    int* __restrict__ gcur,
    unsigned int* __restrict__ cvg, unsigned short* __restrict__ rlg)
{
    __shared__ int hist[NBUCK];
    __shared__ int lofs[NBUCK];
    __shared__ int cnt2[NBUCK];
    __shared__ int gbase[NBUCK];
    __shared__ int sscan[256];
    __shared__ unsigned int   stcv[EPB];
    __shared__ unsigned short strl[EPB];
    __shared__ int            sdst[EPB];

    int t = threadIdx.x;

    for (int base = blockIdx.x * EPB; base < NNZ; base += gridDim.x * EPB) {
        int e1 = min(base + EPB, NNZ);
        int cnt = e1 - base;

        if (t < NBUCK) { hist[t] = 0; cnt2[t] = 0; }
        __syncthreads();

        int myb[8];
        unsigned int mycv[8];
        unsigned short myrl[8];
        #pragma unroll
        for (int u = 0; u < 8; ++u) {
            int idx = base + u * 256 + t;
            myb[u] = -1;
            if (idx < e1) {
                int r = rows[idx];
                int c = cols[idx];
                float v = vals[idx];
                myb[u] = r >> 10;
                unsigned int q14 = (unsigned int)(v * 16383.f + 0.5f);
                mycv[u] = ((unsigned int)c << 14) | q14;
                myrl[u] = (unsigned short)(r & 1023);
                atomicAdd(&hist[myb[u]], 1);
            }
        }
        __syncthreads();

        int hv = (t < NBUCK) ? hist[t] : 0;
        sscan[t] = hv;
        __syncthreads();
        #pragma unroll
        for (int o = 1; o < 256; o <<= 1) {
            int add = (t >= o) ? sscan[t - o] : 0;
            __syncthreads();
            sscan[t] += add;
            __syncthreads();
        }
        if (t < NBUCK) {
            lofs[t] = sscan[t] - hv;
            gbase[t] = atomicAdd(&gcur[t], hv);
        }
        __syncthreads();

        #pragma unroll
        for (int u = 0; u < 8; ++u) {
            if (myb[u] >= 0) {
                int rank = atomicAdd(&cnt2[myb[u]], 1);
                int p = lofs[myb[u]] + rank;
                stcv[p] = mycv[u];
                strl[p] = myrl[u];
                sdst[p] = gbase[myb[u]] + rank;
            }
        }
        __syncthreads();

        for (int j = t; j < cnt; j += 256) {
            int dp = sdst[j];
            cvg[dp] = stcv[j];
            rlg[dp] = strl[j];
        }
        __syncthreads();
    }
}

// ---------------------------------------------------------------------------
__global__ __launch_bounds__(1024) void csr_bucket(
    const int* __restrict__ boff,
    unsigned int* __restrict__ cv, const unsigned short* __restrict__ rl,
    int* __restrict__ off)
{
    __shared__ int curL[BROWS];
    __shared__ int sWaveSum[16];
    __shared__ int sWaveOff[16];

    int b = blockIdx.x;
    int t = threadIdx.x;
    int s = boff[b];
    int e = boff[b + 1];

    unsigned int  ecv[CAPB];
    unsigned short erl[CAPB];
    #pragma unroll
    for (int i = 0; i < CAPB; ++i) {
        int idx = s + i * 1024 + t;
        if (idx < e) { ecv[i] = cv[idx]; erl[i] = rl[idx]; }
    }

    curL[t] = 0;
    __syncthreads();

    #pragma unroll
    for (int i = 0; i < CAPB; ++i) {
        int idx = s + i * 1024 + t;
        if (idx < e) atomicAdd(&curL[(int)erl[i]], 1);
    }
    __syncthreads();

    int lane = t & 63;
    int wid  = t >> 6;
    int v = curL[t];
    int inc = v;
    #pragma unroll
    for (int o = 1; o < 64; o <<= 1) {
        int up = __shfl_up(inc, o);
        if (lane >= o) inc += up;
    }
    if (lane == 63) sWaveSum[wid] = inc;
    __syncthreads();
    if (t < 16) {
        int w = sWaveSum[t];
        int wi = w;
        #pragma unroll
        for (int o = 1; o < 16; o <<= 1) {
            int up = __shfl_up(wi, o);
            if (t >= o) wi += up;
        }
        sWaveOff[t] = wi - w;
    }
    __syncthreads();
    int excl = inc - v + sWaveOff[wid];

    int row = b * BROWS + t;
    if (row < N_NODES) off[row] = s + excl;
    __syncthreads();
    curL[t] = s + excl;
    __syncthreads();

    #pragma unroll
    for (int i = 0; i < CAPB; ++i) {
        int idx = s + i * 1024 + t;
        if (idx < e) {
            int p = atomicAdd(&curL[(int)erl[i]], 1);
            cv[p] = ecv[i];
        }
    }
}

// ---------------------------------------------------------------------------
__global__ __launch_bounds__(256) void scale_edges(
    const uint4* __restrict__ cv4, const float* __restrict__ esc,
    ushort4* __restrict__ wn4)
{
    const float VS = 1.f / 16383.f;
    int i = blockIdx.x * blockDim.x + threadIdx.x;
    if (i >= NNZ / 4) return;
    uint4 c = cv4[i];
    ushort4 w;
    w.x = __half_as_ushort(__float2half((float)(c.x & 16383u) * VS * esc[c.x >> 14]));
    w.y = __half_as_ushort(__float2half((float)(c.y & 16383u) * VS * esc[c.y >> 14]));
    w.z = __half_as_ushort(__float2half((float)(c.z & 16383u) * VS * esc[c.z >> 14]));
    w.w = __half_as_ushort(__float2half((float)(c.w & 16383u) * VS * esc[c.w >> 14]));
    wn4[i] = w;
}

// ---------------------------------------------------------------------------
// dual-row packed-4 gather -> fp16 side buffer
// ---------------------------------------------------------------------------
__device__ __forceinline__ void gstep4d(
    const signed char* __restrict__ ego8,
    unsigned c0, unsigned c1, unsigned c2, unsigned c3,
    unsigned wlo, unsigned whi, unsigned g, unsigned dq,
    int ebase, int mid,
    float& a0, float& a1, float& a2, float& a3,
    float& b0, float& b1, float& b2, float& b3)
{
    unsigned cs = (g & 2u) ? ((g & 1u) ? c3 : c2) : ((g & 1u) ? c1 : c0);
    unsigned wd = (g & 2u) ? whi : wlo;
    unsigned short wh = (g & 1u) ? (unsigned short)(wd >> 16)
                                 : (unsigned short)(wd & 0xFFFFu);
    float w = __half2float(__ushort_as_half(wh));
    bool toA = (ebase + (int)g) < mid;
    float wa = toA ? w : 0.f;
    float wb = toA ? 0.f : w;
    uchar4 x4 = *(const uchar4*)(ego8 + (size_t)(cs >> 14) * EMB + dq * 4u);
    float x0 = (float)(signed char)x4.x;
    float x1 = (float)(signed char)x4.y;
    float x2 = (float)(signed char)x4.z;
    float x3 = (float)(signed char)x4.w;
    a0 = fmaf(wa, x0, a0); b0 = fmaf(wb, x0, b0);
    a1 = fmaf(wa, x1, a1); b1 = fmaf(wb, x1, b1);
    a2 = fmaf(wa, x2, a2); b2 = fmaf(wb, x2, b2);
    a3 = fmaf(wa, x3, a3); b3 = fmaf(wb, x3, b3);
}

__device__ __forceinline__ void gstepmd(
    const signed char* __restrict__ ego8,
    const unsigned int* __restrict__ cv, const unsigned short* __restrict__ wn,
    int e, int hi, int mid, unsigned g, unsigned dq,
    float& a0, float& a1, float& a2, float& a3,
    float& b0, float& b1, float& b2, float& b3)
{
    int idx = e + (int)g;
    int cl = (idx < hi) ? idx : hi - 1;
    unsigned c = cv[cl];
    float w = (idx < hi) ? __half2float(__ushort_as_half(wn[cl])) : 0.f;
    bool toA = idx < mid;
    float wa = toA ? w : 0.f;
    float wb = toA ? 0.f : w;
    uchar4 x4 = *(const uchar4*)(ego8 + (size_t)(c >> 14) * EMB + dq * 4u);
    float x0 = (float)(signed char)x4.x;
    float x1 = (float)(signed char)x4.y;
    float x2 = (float)(signed char)x4.z;
    float x3 = (float)(signed char)x4.w;
    a0 = fmaf(wa, x0, a0); b0 = fmaf(wb, x0, b0);
    a1 = fmaf(wa, x1, a1); b1 = fmaf(wb, x1, b1);
    a2 = fmaf(wa, x2, a2); b2 = fmaf(wb, x2, b2);
    a3 = fmaf(wa, x3, a3); b3 = fmaf(wb, x3, b3);
}

__global__ __launch_bounds__(256, 4) void gather_side(
    const int* __restrict__ off, const unsigned int* __restrict__ cv,
    const unsigned short* __restrict__ wn,
    const signed char* __restrict__ ego8,
    __half* __restrict__ sideH)
{
    int t = threadIdx.x;
    int lane = t & 63;
    unsigned g  = (unsigned)(lane >> 4);    // edge group 0..3
    unsigned dq = (unsigned)(lane & 15);    // dim quad: dims 4dq..4dq+3
    int gw = (int)((blockIdx.x * (size_t)blockDim.x + t) >> 6);
    int nw = (gridDim.x * blockDim.x) >> 6;

    for (int n = gw * 2; n < N_NODES; n += nw * 2) {
        int beg = __builtin_amdgcn_readfirstlane(off[n]);
        int mid = __builtin_amdgcn_readfirstlane(off[n + 1]);
        int end = __builtin_amdgcn_readfirstlane(off[n + 2]);
        float a0 = 0.f, a1 = 0.f, a2 = 0.f, a3 = 0.f;
        float b0 = 0.f, b1 = 0.f, b2 = 0.f, b3 = 0.f;
        int e = beg;
        if (e < end && (e & 3)) {                 // alignment prefix
            int ea = (e + 3) & ~3;
            int ub = (ea < end) ? ea : end;
            gstepmd(ego8, cv, wn, e, ub, mid, g, dq, a0, a1, a2, a3, b0, b1, b2, b3);
            e = ea;
        }
        #pragma unroll 2
        for (; e + 16 <= end; e += 16) {          // combined range, 16-edge chunks
            uint4 ca = *(const uint4*)(cv + e);
            uint4 cb = *(const uint4*)(cv + e + 4);
            uint4 cc = *(const uint4*)(cv + e + 8);
            uint4 cd = *(const uint4*)(cv + e + 12);
            uint2 w0 = *(const uint2*)(wn + e);
            uint2 w1 = *(const uint2*)(wn + e + 4);
            uint2 w2 = *(const uint2*)(wn + e + 8);
            uint2 w3 = *(const uint2*)(wn + e + 12);
            gstep4d(ego8, ca.x, ca.y, ca.z, ca.w, w0.x, w0.y, g, dq, e,      mid, a0, a1, a2, a3, b0, b1, b2, b3);
            gstep4d(ego8, cb.x, cb.y, cb.z, cb.w, w1.x, w1.y, g, dq, e + 4,  mid, a0, a1, a2, a3, b0, b1, b2, b3);
            gstep4d(ego8, cc.x, cc.y, cc.z, cc.w, w2.x, w2.y, g, dq, e + 8,  mid, a0, a1, a2, a3, b0, b1, b2, b3);
            gstep4d(ego8, cd.x, cd.y, cd.z, cd.w, w3.x, w3.y, g, dq, e + 12, mid, a0, a1, a2, a3, b0, b1, b2, b3);
        }
        for (; e < end; e += 4)                   // tail
            gstepmd(ego8, cv, wn, e, end, mid, g, dq, a0, a1, a2, a3, b0, b1, b2, b3);

        a0 += __shfl_xor(a0, 16); a0 += __shfl_xor(a0, 32);
        a1 += __shfl_xor(a1, 16); a1 += __shfl_xor(a1, 32);
        a2 += __shfl_xor(a2, 16); a2 += __shfl_xor(a2, 32);
        a3 += __shfl_xor(a3, 16); a3 += __shfl_xor(a3, 32);
        b0 += __shfl_xor(b0, 16); b0 += __shfl_xor(b0, 32);
        b1 += __shfl_xor(b1, 16); b1 += __shfl_xor(b1, 32);
        b2 += __shfl_xor(b2, 16); b2 += __shfl_xor(b2, 32);
        b3 += __shfl_xor(b3, 16); b3 += __shfl_xor(b3, 32);
        if (g == 0) {
            ushort4 h4;
            h4.x = __half_as_ushort(__float2half(a0));
            h4.y = __half_as_ushort(__float2half(a1));
            h4.z = __half_as_ushort(__float2half(a2));
            h4.w = __half_as_ushort(__float2half(a3));
            *(ushort4*)(sideH + (size_t)n * EMB + dq * 4u) = h4;
            ushort4 p4;
            p4.x = __half_as_ushort(__float2half(b0));
            p4.y = __half_as_ushort(__float2half(b1));
            p4.z = __half_as_ushort(__float2half(b2));
            p4.w = __half_as_ushort(__float2half(b3));
            *(ushort4*)(sideH + (size_t)(n + 1) * EMB + dq * 4u) = p4;
        }
    }
}

// ---------------------------------------------------------------------------
// transform v5: side from fp16 sideH, ego from ego8/esc. Writes NORMALIZED
// output to out slot k+1; requant next ego to ego8/esc if writeNext.
// ---------------------------------------------------------------------------
__global__ __launch_bounds__(256) void transform_v5(
    const float* __restrict__ Wg, const float* __restrict__ bg,
    const float* __restrict__ Wb, const float* __restrict__ bb,
    signed char* __restrict__ ego8, float* __restrict__ esc,
    const __half* __restrict__ sideH,
    float* __restrict__ out, int k, int writeNext)
{
    __shared__ float sS [TILE * LPAD];
    __shared__ float sES[TILE * LPAD];
    __shared__ float rsum[4][TILE];
    __shared__ float rmax[4][TILE];

    int t = threadIdx.x;
    int lane = t & 63;
    int dbase = __builtin_amdgcn_readfirstlane((t >> 6) * 16);

    float* slotK1 = out + (size_t)(k + 1) * EMB;
    int node0 = blockIdx.x * TILE;

    float acc[16];
    #pragma unroll
    for (int di = 0; di < 16; ++di) acc[di] = 0.f;

    int f4 = (t & 7) * 4;
    int nn = t >> 3;

    for (int p = 0; p < 2; ++p) {
        #pragma unroll
        for (int rep = 0; rep < 2; ++rep) {
            int n = nn + 32 * rep;
            ushort4 h4 = *(const ushort4*)(sideH + (size_t)(node0 + n) * EMB + 32 * p + f4);
            uchar4 e4 = *(const uchar4*)(ego8 + (size_t)(node0 + n) * EMB + 32 * p + f4);
            float scn = esc[node0 + n];
            float s0 = __half2float(__ushort_as_half(h4.x));
            float s1 = __half2float(__ushort_as_half(h4.y));
            float s2 = __half2float(__ushort_as_half(h4.z));
            float s3 = __half2float(__ushort_as_half(h4.w));
            int lb = n * LPAD + f4;
            sS [lb + 0] = s0; sS [lb + 1] = s1; sS [lb + 2] = s2; sS [lb + 3] = s3;
            sES[lb + 0] = (float)(signed char)e4.x * scn * s0;
            sES[lb + 1] = (float)(signed char)e4.y * scn * s1;
            sES[lb + 2] = (float)(signed char)e4.z * scn * s2;
            sES[lb + 3] = (float)(signed char)e4.w * scn * s3;
        }
        __syncthreads();

        for (int jj = 0; jj < 32; ++jj) {
            float sv = sS [lane * LPAD + jj];
            float ev = sES[lane * LPAD + jj];
            int j = 32 * p + jj;
            const float* wgrow = Wg + j * EMB + dbase;
            const float* wbrow = Wb + j * EMB + dbase;
            #pragma unroll
            for (int di = 0; di < 16; ++di)
                acc[di] = fmaf(sv, wgrow[di], fmaf(ev, wbrow[di], acc[di]));
        }
        __syncthreads();
    }

    float o[16];
    float ps = 0.f, pm = 0.f;
    #pragma unroll
    for (int di = 0; di < 16; ++di) {
        float v = acc[di] + (bg[dbase + di] + bb[dbase + di]);
        v = (v > 0.f) ? v : 0.2f * v;
        o[di] = v;
        ps = fmaf(v, v, ps);
        pm = fmaxf(pm, fabsf(v));
    }
    int w = t >> 6;
    rsum[w][lane] = ps;
    rmax[w][lane] = pm;
    __syncthreads();
    float tot = rsum[0][lane] + rsum[1][lane] + rsum[2][lane] + rsum[3][lane];
    float mx  = fmaxf(fmaxf(rmax[0][lane], rmax[1][lane]),
                      fmaxf(rmax[2][lane], rmax[3][lane]));
    float scale = 1.f / fmaxf(sqrtf(tot), 1e-12f);

    if (writeNext) {
        float inv = (mx > 0.f) ? 127.f / mx : 0.f;
        unsigned int wd[4];
        #pragma unroll
        for (int q = 0; q < 4; ++q) {
            unsigned int b0 = (unsigned int)(unsigned char)(signed char)__float2int_rn(o[4*q+0] * inv);
            unsigned int b1 = (unsigned int)(unsigned char)(signed char)__float2int_rn(o[4*q+1] * inv);
            unsigned int b2 = (unsigned int)(unsigned char)(signed char)__float2int_rn(o[4*q+2] * inv);
            unsigned int b3 = (unsigned int)(unsigned char)(signed char)__float2int_rn(o[4*q+3] * inv);
            wd[q] = b0 | (b1 << 8) | (b2 << 16) | (b3 << 24);
        }
        uint4 pk; pk.x = wd[0]; pk.y = wd[1]; pk.z = wd[2]; pk.w = wd[3];
        *(uint4*)(ego8 + (size_t)(node0 + lane) * EMB + dbase) = pk;
        if (t < TILE) esc[node0 + lane] = mx * (1.f / 127.f);
    }

    float* dstp = slotK1 + (size_t)(node0 + lane) * ROWSTRIDE + dbase;
    #pragma unroll
    for (int q = 0; q < 4; ++q) {
        float4 o4;
        o4.x = o[4 * q + 0] * scale;
        o4.y = o[4 * q + 1] * scale;
        o4.z = o[4 * q + 2] * scale;
        o4.w = o[4 * q + 3] * scale;
        *(float4*)(dstp + 4 * q) = o4;
    }
}

extern "C" void kernel_launch(void* const* d_in, const int* in_sizes, int n_in,
                              void* d_out, int out_size, void* d_ws, size_t ws_size,
                              hipStream_t stream)
{
    const int*   rows     = (const int*)d_in[0];
    const int*   cols     = (const int*)d_in[1];
    const float* vals     = (const float*)d_in[2];
    const float* user_emb = (const float*)d_in[3];
    const float* item_emb = (const float*)d_in[4];
    const float* W_gc     = (const float*)d_in[5];
    const float* b_gc     = (const float*)d_in[6];
    const float* W_bi     = (const float*)d_in[7];
    const float* b_bi     = (const float*)d_in[8];
    float* out = (float*)d_out;

    // ws: ego8[12.8M] | esc[0.8M] | bcnt|boff|gcur|off|pad | cv[12.8M]
    //     | wn[6.4M] | sideH[25.6M]  (rl aliases sideH: build-only)
    signed char* ego8 = (signed char*)d_ws;
    float* esc = (float*)(ego8 + (size_t)N_NODES * EMB);
    int* bcnt = (int*)(esc + N_NODES);
    int* boff = bcnt + NBUCK;
    int* gcur = boff + NBUCK + 1;
    int* off  = gcur + NBUCK;
    unsigned int* cv = (unsigned int*)(off + N_NODES + 1 + 2);   // 16B aligned
    unsigned short* wn = (unsigned short*)(cv + NNZ);
    __half* sideH = (__half*)(wn + NNZ);
    unsigned short* rl = (unsigned short*)sideH;   // aliased: dead after CSR build

    // --- CSR build ---
    hipMemsetAsync(bcnt, 0, NBUCK * sizeof(int), stream);
    hist_buckets<<<512, 256, 0, stream>>>((const int4*)rows, bcnt);
    scan196<<<1, 256, 0, stream>>>(bcnt, boff, gcur, off);
    bucketize<<<512, 256, 0, stream>>>(rows, cols, vals, gcur, cv, rl);
    csr_bucket<<<NBUCK, 1024, 0, stream>>>(boff, cv, rl, off);

    // --- slot 0 = initial ego (+ int8 mirror) ---
    init_ego_q<<<(N_NODES * 64) / 256, 256, 0, stream>>>(
        user_emb, item_emb, out, ego8, esc);

    // --- hop-0 edge weights ---
    scale_edges<<<(NNZ / 4 + 255) / 256, 256, 0, stream>>>(
        (const uint4*)cv, esc, (ushort4*)wn);

    // --- hops ---
    for (int k = 0; k < HOPS; ++k) {
        gather_side<<<2048, 256, 0, stream>>>(off, cv, wn, ego8, sideH);
        transform_v5<<<N_NODES / TILE, 256, 0, stream>>>(
            W_gc + (size_t)k * EMB * EMB, b_gc + (size_t)k * EMB,
            W_bi + (size_t)k * EMB * EMB, b_bi + (size_t)k * EMB,
            ego8, esc, sideH, out, k, (k < HOPS - 1) ? 1 : 0);
        if (k < HOPS - 1)
            scale_edges<<<(NNZ / 4 + 255) / 256, 256, 0, stream>>>(
                (const uint4*)cv, esc, (ushort4*)wn);
    }
}

// Round 16
// 589.466 us; speedup vs baseline: 1.0676x; 1.0676x over previous
//
#include <hip/hip_runtime.h>
#include <hip/hip_fp16.h>

#define N_USERS 100000
#define N_ITEMS 100000
#define N_NODES 200000
#define NNZ     3200000
#define EMB     64
#define HOPS    3
#define SLOTS   (HOPS + 1)
#define ROWSTRIDE (SLOTS * EMB)   // 256 floats per node row in out

#define BROWS 1024                               // rows per bucket
#define NBUCK ((N_NODES + BROWS - 1) / BROWS)    // 196
#define CAPB  20                                 // reg entries per thread (csr_bucket)
#define EPB   2048                               // edges per round (bucketize)
#define TILE  64                                 // nodes per transform block
#define LPAD  33                                 // LDS row pitch

// CSR entry: cv = (col<<14) | val14 ; ego mirror: int8 + per-row scale esc
// per-hop edge weight: wn[e] = fp16(val * esc[col]) (streaming, rebuilt per hop)

// ---------------------------------------------------------------------------
__global__ __launch_bounds__(256) void init_ego_q(
    const float* __restrict__ user_emb,
    const float* __restrict__ item_emb,
    float* __restrict__ out,
    signed char* __restrict__ ego8, float* __restrict__ esc)
{
    int gid = blockIdx.x * blockDim.x + threadIdx.x;
    int n = gid >> 6;
    int d = gid & 63;
    if (n >= N_NODES) return;
    float v = (n < N_USERS) ? user_emb[(size_t)n * EMB + d]
                            : item_emb[(size_t)(n - N_USERS) * EMB + d];
    out[(size_t)n * ROWSTRIDE + d] = v;

    float mx = fabsf(v);
    #pragma unroll
    for (int o = 32; o > 0; o >>= 1) mx = fmaxf(mx, __shfl_xor(mx, o));
    float inv = (mx > 0.f) ? 127.f / mx : 0.f;
    ego8[(size_t)n * EMB + d] = (signed char)__float2int_rn(v * inv);
    if (d == 0) esc[n] = mx * (1.f / 127.f);
}

// ---------------------------------------------------------------------------
__global__ __launch_bounds__(256) void hist_buckets(
    const int4* __restrict__ rows4, int* __restrict__ bcnt)
{
    __shared__ int h[NBUCK];
    int t = threadIdx.x;
    if (t < NBUCK) h[t] = 0;
    __syncthreads();
    for (int i = blockIdx.x * blockDim.x + t; i < NNZ / 4; i += gridDim.x * blockDim.x) {
        int4 r = rows4[i];
        atomicAdd(&h[r.x >> 10], 1);
        atomicAdd(&h[r.y >> 10], 1);
        atomicAdd(&h[r.z >> 10], 1);
        atomicAdd(&h[r.w >> 10], 1);
    }
    __syncthreads();
    if (t < NBUCK && h[t]) atomicAdd(&bcnt[t], h[t]);
}

// ---------------------------------------------------------------------------
__global__ __launch_bounds__(256) void scan196(
    const int* __restrict__ bcnt, int* __restrict__ boff,
    int* __restrict__ gcur, int* __restrict__ off)
{
    __shared__ int sdata[256];
    int t = threadIdx.x;
    int v = (t < NBUCK) ? bcnt[t] : 0;
    sdata[t] = v;
    __syncthreads();
    #pragma unroll
    for (int ofs = 1; ofs < 256; ofs <<= 1) {
        int add = (t >= ofs) ? sdata[t - ofs] : 0;
        __syncthreads();
        sdata[t] += add;
        __syncthreads();
    }
    if (t < NBUCK) {
        int excl = sdata[t] - v;
        boff[t] = excl;
        gcur[t] = excl;
    }
    if (t == NBUCK - 1) boff[NBUCK] = sdata[t];
    if (t == 0) off[N_NODES] = NNZ;
}

// ---------------------------------------------------------------------------
// bucketize: block-local counting sort; per-round scan is wave-shuffle based
// (2 barriers/round instead of ~16).
// ---------------------------------------------------------------------------
__global__ __launch_bounds__(256) void bucketize(
    const int* __restrict__ rows, const int* __restrict__ cols,
    const float* __restrict__ vals,
    int* __restrict__ gcur,
    unsigned int* __restrict__ cvg, unsigned short* __restrict__ rlg)
{
    __shared__ int hist[NBUCK];
    __shared__ int lofs[NBUCK];
    __shared__ int cnt2[NBUCK];
    __shared__ int gbase[NBUCK];
    __shared__ int wsumS[4];
    __shared__ unsigned int   stcv[EPB];
    __shared__ unsigned short strl[EPB];
    __shared__ int            sdst[EPB];

    int t = threadIdx.x;
    int lane = t & 63;
    int wid  = t >> 6;

    for (int base = blockIdx.x * EPB; base < NNZ; base += gridDim.x * EPB) {
        int e1 = min(base + EPB, NNZ);
        int cnt = e1 - base;

        if (t < NBUCK) { hist[t] = 0; cnt2[t] = 0; }
        __syncthreads();

        int myb[8];
        unsigned int mycv[8];
        unsigned short myrl[8];
        #pragma unroll
        for (int u = 0; u < 8; ++u) {
            int idx = base + u * 256 + t;
            myb[u] = -1;
            if (idx < e1) {
                int r = rows[idx];
                int c = cols[idx];
                float v = vals[idx];
                myb[u] = r >> 10;
                unsigned int q14 = (unsigned int)(v * 16383.f + 0.5f);
                mycv[u] = ((unsigned int)c << 14) | q14;
                myrl[u] = (unsigned short)(r & 1023);
                atomicAdd(&hist[myb[u]], 1);
            }
        }
        __syncthreads();

        // wave-shuffle exclusive scan of hist[0..NBUCK)
        int hv = (t < NBUCK) ? hist[t] : 0;
        int inc = hv;
        #pragma unroll
        for (int o = 1; o < 64; o <<= 1) {
            int up = __shfl_up(inc, o);
            if (lane >= o) inc += up;
        }
        if (lane == 63) wsumS[wid] = inc;
        __syncthreads();
        int woff = 0;
        #pragma unroll
        for (int q = 0; q < 3; ++q) if (wid > q) woff += wsumS[q];
        if (t < NBUCK) {
            lofs[t] = inc - hv + woff;
            gbase[t] = atomicAdd(&gcur[t], hv);
        }
        __syncthreads();

        #pragma unroll
        for (int u = 0; u < 8; ++u) {
            if (myb[u] >= 0) {
                int rank = atomicAdd(&cnt2[myb[u]], 1);
                int p = lofs[myb[u]] + rank;
                stcv[p] = mycv[u];
                strl[p] = myrl[u];
                sdst[p] = gbase[myb[u]] + rank;
            }
        }
        __syncthreads();

        for (int j = t; j < cnt; j += 256) {
            int dp = sdst[j];
            cvg[dp] = stcv[j];
            rlg[dp] = strl[j];
        }
        __syncthreads();
    }
}

// ---------------------------------------------------------------------------
__global__ __launch_bounds__(1024) void csr_bucket(
    const int* __restrict__ boff,
    unsigned int* __restrict__ cv, const unsigned short* __restrict__ rl,
    int* __restrict__ off)
{
    __shared__ int curL[BROWS];
    __shared__ int sWaveSum[16];
    __shared__ int sWaveOff[16];

    int b = blockIdx.x;
    int t = threadIdx.x;
    int s = boff[b];
    int e = boff[b + 1];

    unsigned int  ecv[CAPB];
    unsigned short erl[CAPB];
    #pragma unroll
    for (int i = 0; i < CAPB; ++i) {
        int idx = s + i * 1024 + t;
        if (idx < e) { ecv[i] = cv[idx]; erl[i] = rl[idx]; }
    }

    curL[t] = 0;
    __syncthreads();

    #pragma unroll
    for (int i = 0; i < CAPB; ++i) {
        int idx = s + i * 1024 + t;
        if (idx < e) atomicAdd(&curL[(int)erl[i]], 1);
    }
    __syncthreads();

    int lane = t & 63;
    int wid  = t >> 6;
    int v = curL[t];
    int inc = v;
    #pragma unroll
    for (int o = 1; o < 64; o <<= 1) {
        int up = __shfl_up(inc, o);
        if (lane >= o) inc += up;
    }
    if (lane == 63) sWaveSum[wid] = inc;
    __syncthreads();
    if (t < 16) {
        int w = sWaveSum[t];
        int wi = w;
        #pragma unroll
        for (int o = 1; o < 16; o <<= 1) {
            int up = __shfl_up(wi, o);
            if (t >= o) wi += up;
        }
        sWaveOff[t] = wi - w;
    }
    __syncthreads();
    int excl = inc - v + sWaveOff[wid];

    int row = b * BROWS + t;
    if (row < N_NODES) off[row] = s + excl;
    __syncthreads();
    curL[t] = s + excl;
    __syncthreads();

    #pragma unroll
    for (int i = 0; i < CAPB; ++i) {
        int idx = s + i * 1024 + t;
        if (idx < e) {
            int p = atomicAdd(&curL[(int)erl[i]], 1);
            cv[p] = ecv[i];
        }
    }
}

// ---------------------------------------------------------------------------
__global__ __launch_bounds__(256) void scale_edges(
    const uint4* __restrict__ cv4, const float* __restrict__ esc,
    ushort4* __restrict__ wn4)
{
    const float VS = 1.f / 16383.f;
    int i = blockIdx.x * blockDim.x + threadIdx.x;
    if (i >= NNZ / 4) return;
    uint4 c = cv4[i];
    ushort4 w;
    w.x = __half_as_ushort(__float2half((float)(c.x & 16383u) * VS * esc[c.x >> 14]));
    w.y = __half_as_ushort(__float2half((float)(c.y & 16383u) * VS * esc[c.y >> 14]));
    w.z = __half_as_ushort(__float2half((float)(c.z & 16383u) * VS * esc[c.z >> 14]));
    w.w = __half_as_ushort(__float2half((float)(c.w & 16383u) * VS * esc[c.w >> 14]));
    wn4[i] = w;
}

// ---------------------------------------------------------------------------
// dual-row packed-4 gather: a wave owns rows (n, n+1); combined CSR range
// walked in 16-edge chunks; contributions steered by predicated weights.
// ---------------------------------------------------------------------------
__device__ __forceinline__ void gstep4d(
    const signed char* __restrict__ ego8,
    unsigned c0, unsigned c1, unsigned c2, unsigned c3,
    unsigned wlo, unsigned whi, unsigned g, unsigned dq,
    int ebase, int mid,
    float& a0, float& a1, float& a2, float& a3,
    float& b0, float& b1, float& b2, float& b3)
{
    unsigned cs = (g & 2u) ? ((g & 1u) ? c3 : c2) : ((g & 1u) ? c1 : c0);
    unsigned wd = (g & 2u) ? whi : wlo;
    unsigned short wh = (g & 1u) ? (unsigned short)(wd >> 16)
                                 : (unsigned short)(wd & 0xFFFFu);
    float w = __half2float(__ushort_as_half(wh));
    bool toA = (ebase + (int)g) < mid;
    float wa = toA ? w : 0.f;
    float wb = toA ? 0.f : w;
    uchar4 x4 = *(const uchar4*)(ego8 + (size_t)(cs >> 14) * EMB + dq * 4u);
    float x0 = (float)(signed char)x4.x;
    float x1 = (float)(signed char)x4.y;
    float x2 = (float)(signed char)x4.z;
    float x3 = (float)(signed char)x4.w;
    a0 = fmaf(wa, x0, a0); b0 = fmaf(wb, x0, b0);
    a1 = fmaf(wa, x1, a1); b1 = fmaf(wb, x1, b1);
    a2 = fmaf(wa, x2, a2); b2 = fmaf(wb, x2, b2);
    a3 = fmaf(wa, x3, a3); b3 = fmaf(wb, x3, b3);
}

__device__ __forceinline__ void gstepmd(
    const signed char* __restrict__ ego8,
    const unsigned int* __restrict__ cv, const unsigned short* __restrict__ wn,
    int e, int hi, int mid, unsigned g, unsigned dq,
    float& a0, float& a1, float& a2, float& a3,
    float& b0, float& b1, float& b2, float& b3)
{
    int idx = e + (int)g;
    int cl = (idx < hi) ? idx : hi - 1;
    unsigned c = cv[cl];
    float w = (idx < hi) ? __half2float(__ushort_as_half(wn[cl])) : 0.f;
    bool toA = idx < mid;
    float wa = toA ? w : 0.f;
    float wb = toA ? 0.f : w;
    uchar4 x4 = *(const uchar4*)(ego8 + (size_t)(c >> 14) * EMB + dq * 4u);
    float x0 = (float)(signed char)x4.x;
    float x1 = (float)(signed char)x4.y;
    float x2 = (float)(signed char)x4.z;
    float x3 = (float)(signed char)x4.w;
    a0 = fmaf(wa, x0, a0); b0 = fmaf(wb, x0, b0);
    a1 = fmaf(wa, x1, a1); b1 = fmaf(wb, x1, b1);
    a2 = fmaf(wa, x2, a2); b2 = fmaf(wb, x2, b2);
    a3 = fmaf(wa, x3, a3); b3 = fmaf(wb, x3, b3);
}

__global__ __launch_bounds__(256, 4) void gather_side(
    const int* __restrict__ off, const unsigned int* __restrict__ cv,
    const unsigned short* __restrict__ wn,
    const signed char* __restrict__ ego8,
    float* __restrict__ out, int k)
{
    int t = threadIdx.x;
    int lane = t & 63;
    unsigned g  = (unsigned)(lane >> 4);    // edge group 0..3
    unsigned dq = (unsigned)(lane & 15);    // dim quad: dims 4dq..4dq+3
    int gw = (int)((blockIdx.x * (size_t)blockDim.x + t) >> 6);
    int nw = (gridDim.x * blockDim.x) >> 6;

    float* dst = out + (size_t)(k + 1) * EMB;

    for (int n = gw * 2; n < N_NODES; n += nw * 2) {
        int beg = __builtin_amdgcn_readfirstlane(off[n]);
        int mid = __builtin_amdgcn_readfirstlane(off[n + 1]);
        int end = __builtin_amdgcn_readfirstlane(off[n + 2]);
        float a0 = 0.f, a1 = 0.f, a2 = 0.f, a3 = 0.f;
        float b0 = 0.f, b1 = 0.f, b2 = 0.f, b3 = 0.f;
        int e = beg;
        if (e < end && (e & 3)) {                 // alignment prefix
            int ea = (e + 3) & ~3;
            int ub = (ea < end) ? ea : end;
            gstepmd(ego8, cv, wn, e, ub, mid, g, dq, a0, a1, a2, a3, b0, b1, b2, b3);
            e = ea;
        }
        #pragma unroll 2
        for (; e + 16 <= end; e += 16) {          // combined range, 16-edge chunks
            uint4 ca = *(const uint4*)(cv + e);
            uint4 cb = *(const uint4*)(cv + e + 4);
            uint4 cc = *(const uint4*)(cv + e + 8);
            uint4 cd = *(const uint4*)(cv + e + 12);
            uint2 w0 = *(const uint2*)(wn + e);
            uint2 w1 = *(const uint2*)(wn + e + 4);
            uint2 w2 = *(const uint2*)(wn + e + 8);
            uint2 w3 = *(const uint2*)(wn + e + 12);
            gstep4d(ego8, ca.x, ca.y, ca.z, ca.w, w0.x, w0.y, g, dq, e,      mid, a0, a1, a2, a3, b0, b1, b2, b3);
            gstep4d(ego8, cb.x, cb.y, cb.z, cb.w, w1.x, w1.y, g, dq, e + 4,  mid, a0, a1, a2, a3, b0, b1, b2, b3);
            gstep4d(ego8, cc.x, cc.y, cc.z, cc.w, w2.x, w2.y, g, dq, e + 8,  mid, a0, a1, a2, a3, b0, b1, b2, b3);
            gstep4d(ego8, cd.x, cd.y, cd.z, cd.w, w3.x, w3.y, g, dq, e + 12, mid, a0, a1, a2, a3, b0, b1, b2, b3);
        }
        for (; e < end; e += 4)                   // tail
            gstepmd(ego8, cv, wn, e, end, mid, g, dq, a0, a1, a2, a3, b0, b1, b2, b3);

        // fold 4 group-partials for both rows
        a0 += __shfl_xor(a0, 16); a0 += __shfl_xor(a0, 32);
        a1 += __shfl_xor(a1, 16); a1 += __shfl_xor(a1, 32);
        a2 += __shfl_xor(a2, 16); a2 += __shfl_xor(a2, 32);
        a3 += __shfl_xor(a3, 16); a3 += __shfl_xor(a3, 32);
        b0 += __shfl_xor(b0, 16); b0 += __shfl_xor(b0, 32);
        b1 += __shfl_xor(b1, 16); b1 += __shfl_xor(b1, 32);
        b2 += __shfl_xor(b2, 16); b2 += __shfl_xor(b2, 32);
        b3 += __shfl_xor(b3, 16); b3 += __shfl_xor(b3, 32);
        if (g == 0) {
            float4 o4; o4.x = a0; o4.y = a1; o4.z = a2; o4.w = a3;
            *(float4*)(dst + (size_t)n * ROWSTRIDE + dq * 4u) = o4;
            float4 p4; p4.x = b0; p4.y = b1; p4.z = b2; p4.w = b3;
            *(float4*)(dst + (size_t)(n + 1) * ROWSTRIDE + dq * 4u) = p4;
        }
    }
}

// ---------------------------------------------------------------------------
// transform v4: block = 64-node tile, 4 waves; lane = node, wave owns 16 dims.
// ---------------------------------------------------------------------------
__global__ __launch_bounds__(256) void transform_v4(
    const float* __restrict__ Wg, const float* __restrict__ bg,
    const float* __restrict__ Wb, const float* __restrict__ bb,
    signed char* __restrict__ ego8, float* __restrict__ esc,
    float* __restrict__ out, int k, int writeNext)
{
    __shared__ float sS [TILE * LPAD];
    __shared__ float sES[TILE * LPAD];
    __shared__ float rsum[4][TILE];
    __shared__ float rmax[4][TILE];

    int t = threadIdx.x;
    int lane = t & 63;
    int dbase = __builtin_amdgcn_readfirstlane((t >> 6) * 16);

    float* slotK1 = out + (size_t)(k + 1) * EMB;
    int node0 = blockIdx.x * TILE;

    float acc[16];
    #pragma unroll
    for (int di = 0; di < 16; ++di) acc[di] = 0.f;

    int f4 = (t & 7) * 4;
    int nn = t >> 3;

    for (int p = 0; p < 2; ++p) {
        #pragma unroll
        for (int rep = 0; rep < 2; ++rep) {
            int n = nn + 32 * rep;
            size_t sbase = (size_t)(node0 + n) * ROWSTRIDE + 32 * p + f4;
            float4 s4 = *(const float4*)(slotK1 + sbase);
            uchar4 e4 = *(const uchar4*)(ego8 + (size_t)(node0 + n) * EMB + 32 * p + f4);
            float scn = esc[node0 + n];
            int lb = n * LPAD + f4;
            sS [lb + 0] = s4.x; sS [lb + 1] = s4.y; sS [lb + 2] = s4.z; sS [lb + 3] = s4.w;
            sES[lb + 0] = (float)(signed char)e4.x * scn * s4.x;
            sES[lb + 1] = (float)(signed char)e4.y * scn * s4.y;
            sES[lb + 2] = (float)(signed char)e4.z * scn * s4.z;
            sES[lb + 3] = (float)(signed char)e4.w * scn * s4.w;
        }
        __syncthreads();

        for (int jj = 0; jj < 32; ++jj) {
            float sv = sS [lane * LPAD + jj];
            float ev = sES[lane * LPAD + jj];
            int j = 32 * p + jj;
            const float* wgrow = Wg + j * EMB + dbase;
            const float* wbrow = Wb + j * EMB + dbase;
            #pragma unroll
            for (int di = 0; di < 16; ++di)
                acc[di] = fmaf(sv, wgrow[di], fmaf(ev, wbrow[di], acc[di]));
        }
        __syncthreads();
    }

    float o[16];
    float ps = 0.f, pm = 0.f;
    #pragma unroll
    for (int di = 0; di < 16; ++di) {
        float v = acc[di] + (bg[dbase + di] + bb[dbase + di]);
        v = (v > 0.f) ? v : 0.2f * v;
        o[di] = v;
        ps = fmaf(v, v, ps);
        pm = fmaxf(pm, fabsf(v));
    }
    int w = t >> 6;
    rsum[w][lane] = ps;
    rmax[w][lane] = pm;
    __syncthreads();
    float tot = rsum[0][lane] + rsum[1][lane] + rsum[2][lane] + rsum[3][lane];
    float mx  = fmaxf(fmaxf(rmax[0][lane], rmax[1][lane]),
                      fmaxf(rmax[2][lane], rmax[3][lane]));
    float scale = 1.f / fmaxf(sqrtf(tot), 1e-12f);

    if (writeNext) {
        float inv = (mx > 0.f) ? 127.f / mx : 0.f;
        unsigned int wd[4];
        #pragma unroll
        for (int q = 0; q < 4; ++q) {
            unsigned int b0 = (unsigned int)(unsigned char)(signed char)__float2int_rn(o[4*q+0] * inv);
            unsigned int b1 = (unsigned int)(unsigned char)(signed char)__float2int_rn(o[4*q+1] * inv);
            unsigned int b2 = (unsigned int)(unsigned char)(signed char)__float2int_rn(o[4*q+2] * inv);
            unsigned int b3 = (unsigned int)(unsigned char)(signed char)__float2int_rn(o[4*q+3] * inv);
            wd[q] = b0 | (b1 << 8) | (b2 << 16) | (b3 << 24);
        }
        uint4 pk; pk.x = wd[0]; pk.y = wd[1]; pk.z = wd[2]; pk.w = wd[3];
        *(uint4*)(ego8 + (size_t)(node0 + lane) * EMB + dbase) = pk;
        if (t < TILE) esc[node0 + lane] = mx * (1.f / 127.f);
    }

    float* dstp = slotK1 + (size_t)(node0 + lane) * ROWSTRIDE + dbase;
    #pragma unroll
    for (int q = 0; q < 4; ++q) {
        float4 o4;
        o4.x = o[4 * q + 0] * scale;
        o4.y = o[4 * q + 1] * scale;
        o4.z = o[4 * q + 2] * scale;
        o4.w = o[4 * q + 3] * scale;
        *(float4*)(dstp + 4 * q) = o4;
    }
}

extern "C" void kernel_launch(void* const* d_in, const int* in_sizes, int n_in,
                              void* d_out, int out_size, void* d_ws, size_t ws_size,
                              hipStream_t stream)
{
    const int*   rows     = (const int*)d_in[0];
    const int*   cols     = (const int*)d_in[1];
    const float* vals     = (const float*)d_in[2];
    const float* user_emb = (const float*)d_in[3];
    const float* item_emb = (const float*)d_in[4];
    const float* W_gc     = (const float*)d_in[5];
    const float* b_gc     = (const float*)d_in[6];
    const float* W_bi     = (const float*)d_in[7];
    const float* b_bi     = (const float*)d_in[8];
    float* out = (float*)d_out;

    // ws: ego8[12.8M] | esc[0.8M] | bcnt|boff|gcur|off|pad | cv[12.8M, 16B-aligned]
    //     | wn[6.4M] | rl[6.4M]   (total ~40 MB)
    signed char* ego8 = (signed char*)d_ws;
    float* esc = (float*)(ego8 + (size_t)N_NODES * EMB);
    int* bcnt = (int*)(esc + N_NODES);
    int* boff = bcnt + NBUCK;
    int* gcur = boff + NBUCK + 1;
    int* off  = gcur + NBUCK;
    unsigned int* cv = (unsigned int*)(off + N_NODES + 1 + 2);   // 16B aligned
    unsigned short* wn = (unsigned short*)(cv + NNZ);
    unsigned short* rl = wn + NNZ;

    // --- CSR build ---
    hipMemsetAsync(bcnt, 0, NBUCK * sizeof(int), stream);
    hist_buckets<<<512, 256, 0, stream>>>((const int4*)rows, bcnt);
    scan196<<<1, 256, 0, stream>>>(bcnt, boff, gcur, off);
    bucketize<<<512, 256, 0, stream>>>(rows, cols, vals, gcur, cv, rl);
    csr_bucket<<<NBUCK, 1024, 0, stream>>>(boff, cv, rl, off);

    // --- slot 0 = initial ego (+ int8 mirror) ---
    init_ego_q<<<(N_NODES * 64) / 256, 256, 0, stream>>>(
        user_emb, item_emb, out, ego8, esc);

    // --- hop-0 edge weights ---
    scale_edges<<<(NNZ / 4 + 255) / 256, 256, 0, stream>>>(
        (const uint4*)cv, esc, (ushort4*)wn);

    // --- hops ---
    for (int k = 0; k < HOPS; ++k) {
        gather_side<<<2048, 256, 0, stream>>>(off, cv, wn, ego8, out, k);
        transform_v4<<<N_NODES / TILE, 256, 0, stream>>>(
            W_gc + (size_t)k * EMB * EMB, b_gc + (size_t)k * EMB,
            W_bi + (size_t)k * EMB * EMB, b_bi + (size_t)k * EMB,
            ego8, esc, out, k, (k < HOPS - 1) ? 1 : 0);
        if (k < HOPS - 1)
            scale_edges<<<(NNZ / 4 + 255) / 256, 256, 0, stream>>>(
                (const uint4*)cv, esc, (ushort4*)wn);
    }
}